// Round 3
// baseline (1644.661 us; speedup 1.0000x reference)
//
#include <hip/hip_runtime.h>
#include <math.h>

#define EPS 1e-7f
#define MAX_NORM (1.0f - 1e-5f)

__device__ __forceinline__ float waveReduceSum(float v) {
    // full 64-lane butterfly reduction
    #pragma unroll
    for (int off = 32; off > 0; off >>= 1) v += __shfl_xor(v, off, 64);
    return v;
}

// ---------------------------------------------------------------------------
// Phase 1: hyperbolic transform
//   w_h = expmap0(weight)         (per-row of [64,64])
//   h   = mobius_matvec(w_h, x)   (one wave per row of x)
//   h   = mobius_add(h, expmap0(bias))
// ---------------------------------------------------------------------------
__global__ __launch_bounds__(256) void transform_kernel(
    const float* __restrict__ x, const float* __restrict__ weight,
    const float* __restrict__ bias, float* __restrict__ h, int N)
{
    __shared__ float wlds[64 * 64];
    __shared__ float bh[64];

    const int tid  = threadIdx.x;
    const int lane = tid & 63;
    const int wave = tid >> 6;

    // load raw weight into LDS
    for (int idx = tid; idx < 64 * 64; idx += 256) wlds[idx] = weight[idx];
    __syncthreads();

    // expmap0 on each row of weight (in place in LDS).
    // Each lane touches only its own element -> no intra-wave hazard.
    for (int r = wave; r < 64; r += 4) {
        float v  = wlds[r * 64 + lane];
        float ss = waveReduceSum(v * v);
        float n  = fmaxf(sqrtf(ss), EPS);
        float s  = tanhf(n) / n;
        wlds[r * 64 + lane] = v * s;
    }
    if (wave == 0) {
        float b  = bias[lane];
        float ss = waveReduceSum(b * b);
        float n  = fmaxf(sqrtf(ss), EPS);
        bh[lane] = b * (tanhf(n) / n);
    }
    __syncthreads();

    const float bd = bh[lane];
    const float y2 = waveReduceSum(bd * bd);

    const int gw = blockIdx.x * 4 + wave;
    const int nw = gridDim.x * 4;
    for (int i = gw; i < N; i += nw) {
        const float* xrow = x + (size_t)i * 64;
        // row norm
        float xv = xrow[lane];
        float ss = waveReduceSum(xv * xv);
        float xn = fmaxf(sqrtf(ss), EPS);
        // artanh with the reference's clip
        float xc = fminf(xn, 1.0f - 1e-7f);
        float at = 0.5f * log1pf(2.0f * xc / (1.0f - xc));
        // Mx[lane] = sum_k x[k] * w_h[k][lane]; xrow[k] is wave-uniform
        float acc = 0.0f;
        #pragma unroll
        for (int k = 0; k < 64; ++k)
            acc = fmaf(xrow[k], wlds[k * 64 + lane], acc);
        float mss = waveReduceSum(acc * acc);
        float mxn = fmaxf(sqrtf(mss), EPS);
        float hv  = acc * (tanhf(mxn / xn * at) / mxn);
        // mobius_add(hv, bh)
        float x2 = waveReduceSum(hv * hv);
        float xy = waveReduceSum(hv * bd);
        float num = (1.0f + 2.0f * xy + y2) * hv + (1.0f - x2) * bd;
        float den = 1.0f + 2.0f * xy + x2 * y2;
        hv = num / fmaxf(den, EPS);
        h[(size_t)i * 64 + lane] = hv;
    }
}

// ---------------------------------------------------------------------------
// Phase 2: edge scatter with fp32 atomics.
// 16 lanes per edge; lane g handles dims [4g, 4g+4): float4 gather + 4 atomics.
// ---------------------------------------------------------------------------
__global__ __launch_bounds__(256) void scatter_kernel(
    const int* __restrict__ ei, const float* __restrict__ h,
    float* __restrict__ out, float* __restrict__ deg, int E)
{
    const long long total  = (long long)E * 16;
    const long long stride = (long long)gridDim.x * blockDim.x;
    for (long long t = (long long)blockIdx.x * blockDim.x + threadIdx.x;
         t < total; t += stride) {
        const int e = (int)(t >> 4);
        const int g = (int)(t & 15);
        const int src = ei[e];
        const int dst = ei[E + e];
        const float4 v = *reinterpret_cast<const float4*>(h + (size_t)src * 64 + g * 4);
        float* o = out + (size_t)dst * 64 + g * 4;
        atomicAdd(o + 0, v.x);
        atomicAdd(o + 1, v.y);
        atomicAdd(o + 2, v.z);
        atomicAdd(o + 3, v.w);
        if (g == 0) atomicAdd(deg + dst, 1.0f);
    }
}

// ---------------------------------------------------------------------------
// Phase 3: out = project(out / max(deg,1))   (one wave per row, in place)
// ---------------------------------------------------------------------------
__global__ __launch_bounds__(256) void finalize_kernel(
    float* __restrict__ out, const float* __restrict__ deg, int N)
{
    const int lane = threadIdx.x & 63;
    const int wave = threadIdx.x >> 6;
    const int gw = blockIdx.x * 4 + wave;
    const int nw = gridDim.x * 4;
    for (int i = gw; i < N; i += nw) {
        float d = fmaxf(deg[i], 1.0f);
        float v = out[(size_t)i * 64 + lane] / d;
        float ss = waveReduceSum(v * v);
        float n  = fmaxf(sqrtf(ss), EPS);
        if (n > MAX_NORM) v = v / n * MAX_NORM;
        out[(size_t)i * 64 + lane] = v;
    }
}

extern "C" void kernel_launch(void* const* d_in, const int* in_sizes, int n_in,
                              void* d_out, int out_size, void* d_ws, size_t ws_size,
                              hipStream_t stream)
{
    const float* x      = (const float*)d_in[0];
    const float* weight = (const float*)d_in[1];
    const float* bias   = (const float*)d_in[2];
    const int*   ei     = (const int*)d_in[3];
    const int N = in_sizes[0] / 64;
    const int E = in_sizes[3] / 2;

    float* out = (float*)d_out;
    float* h   = (float*)d_ws;                 // N*64 floats = 25.6 MB
    float* deg = h + (size_t)N * 64;           // N floats    =  0.4 MB

    // out accumulates atomically -> must start at zero (poisoned 0xAA by harness)
    hipMemsetAsync(d_out, 0, (size_t)out_size * sizeof(float), stream);
    hipMemsetAsync(deg, 0, (size_t)N * sizeof(float), stream);

    transform_kernel<<<2048, 256, 0, stream>>>(x, weight, bias, h, N);
    scatter_kernel<<<2048, 256, 0, stream>>>(ei, h, out, deg, E);
    finalize_kernel<<<512, 256, 0, stream>>>(out, deg, N);
}

// Round 7
// 467.966 us; speedup vs baseline: 3.5145x; 3.5145x over previous
//
#include <hip/hip_runtime.h>
#include <math.h>

#define EPS 1e-7f
#define MAX_NORM (1.0f - 1e-5f)
#define SCAN_CHUNK 1024   // elements per scan block (256 thr x 4)

__device__ __forceinline__ float waveReduceSum(float v) {
    #pragma unroll
    for (int off = 32; off > 0; off >>= 1) v += __shfl_xor(v, off, 64);
    return v;
}

// ---------------------------------------------------------------------------
// Phase 1: hyperbolic transform (unchanged from baseline)
// ---------------------------------------------------------------------------
__global__ __launch_bounds__(256) void transform_kernel(
    const float* __restrict__ x, const float* __restrict__ weight,
    const float* __restrict__ bias, float* __restrict__ h, int N)
{
    __shared__ float wlds[64 * 64];
    __shared__ float bh[64];

    const int tid  = threadIdx.x;
    const int lane = tid & 63;
    const int wave = tid >> 6;

    for (int idx = tid; idx < 64 * 64; idx += 256) wlds[idx] = weight[idx];
    __syncthreads();

    for (int r = wave; r < 64; r += 4) {
        float v  = wlds[r * 64 + lane];
        float ss = waveReduceSum(v * v);
        float n  = fmaxf(sqrtf(ss), EPS);
        wlds[r * 64 + lane] = v * (tanhf(n) / n);
    }
    if (wave == 0) {
        float b  = bias[lane];
        float ss = waveReduceSum(b * b);
        float n  = fmaxf(sqrtf(ss), EPS);
        bh[lane] = b * (tanhf(n) / n);
    }
    __syncthreads();

    const float bd = bh[lane];
    const float y2 = waveReduceSum(bd * bd);

    const int gw = blockIdx.x * 4 + wave;
    const int nw = gridDim.x * 4;
    for (int i = gw; i < N; i += nw) {
        const float* xrow = x + (size_t)i * 64;
        float xv = xrow[lane];
        float ss = waveReduceSum(xv * xv);
        float xn = fmaxf(sqrtf(ss), EPS);
        float xc = fminf(xn, 1.0f - 1e-7f);
        float at = 0.5f * log1pf(2.0f * xc / (1.0f - xc));
        float acc = 0.0f;
        #pragma unroll
        for (int k = 0; k < 64; ++k)
            acc = fmaf(xrow[k], wlds[k * 64 + lane], acc);
        float mss = waveReduceSum(acc * acc);
        float mxn = fmaxf(sqrtf(mss), EPS);
        float hv  = acc * (tanhf(mxn / xn * at) / mxn);
        float x2 = waveReduceSum(hv * hv);
        float xy = waveReduceSum(hv * bd);
        float num = (1.0f + 2.0f * xy + y2) * hv + (1.0f - x2) * bd;
        float den = 1.0f + 2.0f * xy + x2 * y2;
        h[(size_t)i * 64 + lane] = num / fmaxf(den, EPS);
    }
}

// ---------------------------------------------------------------------------
// Phase 2a: degree histogram (int atomics only)
// ---------------------------------------------------------------------------
__global__ __launch_bounds__(256) void hist_kernel(
    const int* __restrict__ dst, int* __restrict__ cnt, int E)
{
    const int stride = gridDim.x * blockDim.x;
    for (int e = blockIdx.x * blockDim.x + threadIdx.x; e < E; e += stride)
        atomicAdd(&cnt[dst[e]], 1);
}

// ---------------------------------------------------------------------------
// Phase 2b: exclusive scan of cnt[0..n) -> pre[0..n), chunk totals -> part[]
// ---------------------------------------------------------------------------
__global__ __launch_bounds__(256) void scan_partial(
    const int* __restrict__ cnt, int* __restrict__ pre,
    int* __restrict__ part, int n)
{
    __shared__ int s[256];
    const int tid  = threadIdx.x;
    const int base = blockIdx.x * SCAN_CHUNK + tid * 4;
    int v0 = (base + 0 < n) ? cnt[base + 0] : 0;
    int v1 = (base + 1 < n) ? cnt[base + 1] : 0;
    int v2 = (base + 2 < n) ? cnt[base + 2] : 0;
    int v3 = (base + 3 < n) ? cnt[base + 3] : 0;
    int tsum = v0 + v1 + v2 + v3;
    s[tid] = tsum;
    __syncthreads();
    for (int off = 1; off < 256; off <<= 1) {
        int t = (tid >= off) ? s[tid - off] : 0;
        __syncthreads();
        s[tid] += t;
        __syncthreads();
    }
    int excl = s[tid] - tsum;             // exclusive prefix of thread sums
    if (base + 0 < n) pre[base + 0] = excl;
    if (base + 1 < n) pre[base + 1] = excl + v0;
    if (base + 2 < n) pre[base + 2] = excl + v0 + v1;
    if (base + 3 < n) pre[base + 3] = excl + v0 + v1 + v2;
    if (tid == 255) part[blockIdx.x] = s[255];
}

__global__ __launch_bounds__(256) void scan_parts(int* __restrict__ part, int nPart)
{
    __shared__ int s[256];
    const int tid = threadIdx.x;
    int v = (tid < nPart) ? part[tid] : 0;
    s[tid] = v;
    __syncthreads();
    for (int off = 1; off < 256; off <<= 1) {
        int t = (tid >= off) ? s[tid - off] : 0;
        __syncthreads();
        s[tid] += t;
        __syncthreads();
    }
    if (tid < nPart) part[tid] = s[tid] - v;  // exclusive
}

__global__ __launch_bounds__(256) void scan_add(
    int* __restrict__ pre, int* __restrict__ cursor,
    const int* __restrict__ part, int n)
{
    const int stride = gridDim.x * blockDim.x;
    for (int i = blockIdx.x * blockDim.x + threadIdx.x; i < n; i += stride) {
        int v = pre[i] + part[i / SCAN_CHUNK];
        pre[i] = v;        // rowptr
        cursor[i] = v;     // bucket cursor (consumed by bucket_kernel)
    }
}

// ---------------------------------------------------------------------------
// Phase 2c: scatter src ids into dst-sorted buckets
// ---------------------------------------------------------------------------
__global__ __launch_bounds__(256) void bucket_kernel(
    const int* __restrict__ src, const int* __restrict__ dst,
    int* __restrict__ cursor, int* __restrict__ bucket, int E)
{
    const int stride = gridDim.x * blockDim.x;
    for (int e = blockIdx.x * blockDim.x + threadIdx.x; e < E; e += stride) {
        int pos = atomicAdd(&cursor[dst[e]], 1);
        bucket[pos] = src[e];
    }
}

// ---------------------------------------------------------------------------
// Phase 3: per-node gather-reduce + mean + projection (fused finalize).
// One wave per node; 64 lanes = 64 dims.
// ---------------------------------------------------------------------------
__global__ __launch_bounds__(256) void gather_reduce_kernel(
    const int* __restrict__ rowptr, const int* __restrict__ cnt,
    const int* __restrict__ bucket, const float* __restrict__ h,
    float* __restrict__ out, int N)
{
    const int lane = threadIdx.x & 63;
    const int wave = threadIdx.x >> 6;
    const int i = blockIdx.x * 4 + wave;
    if (i >= N) return;

    const int start = rowptr[i];
    const int deg   = cnt[i];
    const int end   = start + deg;

    float acc = 0.0f;
    for (int c = start; c < end; c += 64) {
        const int m  = min(64, end - c);
        const int my = (lane < m) ? bucket[c + lane] : 0;
        for (int j = 0; j < m; ++j) {
            const int s = __shfl(my, j, 64);
            acc += h[(size_t)s * 64 + lane];
        }
    }

    float v = acc / fmaxf((float)deg, 1.0f);
    float ss = waveReduceSum(v * v);
    float n  = fmaxf(sqrtf(ss), EPS);
    if (n > MAX_NORM) v = v / n * MAX_NORM;
    out[(size_t)i * 64 + lane] = v;
}

extern "C" void kernel_launch(void* const* d_in, const int* in_sizes, int n_in,
                              void* d_out, int out_size, void* d_ws, size_t ws_size,
                              hipStream_t stream)
{
    const float* x      = (const float*)d_in[0];
    const float* weight = (const float*)d_in[1];
    const float* bias   = (const float*)d_in[2];
    const int*   ei     = (const int*)d_in[3];
    const int N = in_sizes[0] / 64;
    const int E = in_sizes[3] / 2;
    const int* src = ei;
    const int* dst = ei + E;

    float* out = (float*)d_out;

    // workspace layout (~33 MB)
    float* h      = (float*)d_ws;            // N*64 floats
    int*   cnt    = (int*)(h + (size_t)N * 64); // N
    int*   rowptr = cnt + N;                 // N
    int*   cursor = rowptr + N;              // N
    int*   part   = cursor + N;              // 256
    int*   bucket = part + 256;              // E

    const int nPart = (N + SCAN_CHUNK - 1) / SCAN_CHUNK;   // 98 for N=100K

    hipMemsetAsync(cnt, 0, (size_t)N * sizeof(int), stream);

    transform_kernel<<<2048, 256, 0, stream>>>(x, weight, bias, h, N);
    hist_kernel<<<2048, 256, 0, stream>>>(dst, cnt, E);
    scan_partial<<<nPart, 256, 0, stream>>>(cnt, rowptr, part, N);
    scan_parts<<<1, 256, 0, stream>>>(part, nPart);
    scan_add<<<256, 256, 0, stream>>>(rowptr, cursor, part, N);
    bucket_kernel<<<2048, 256, 0, stream>>>(src, dst, cursor, bucket, E);
    gather_reduce_kernel<<<(N + 3) / 4, 256, 0, stream>>>(rowptr, cnt, bucket, h, out, N);
}

// Round 8
// 423.913 us; speedup vs baseline: 3.8797x; 1.1039x over previous
//
#include <hip/hip_runtime.h>
#include <math.h>

#define EPS 1e-7f
#define MAX_NORM (1.0f - 1e-5f)
#define SCAN_CHUNK 1024   // elements per scan block (256 thr x 4)

__device__ __forceinline__ float waveReduceSum(float v) {
    #pragma unroll
    for (int off = 32; off > 0; off >>= 1) v += __shfl_xor(v, off, 64);
    return v;
}

// ---------------------------------------------------------------------------
// Phase 1: hyperbolic transform (unchanged)
// ---------------------------------------------------------------------------
__global__ __launch_bounds__(256) void transform_kernel(
    const float* __restrict__ x, const float* __restrict__ weight,
    const float* __restrict__ bias, float* __restrict__ h, int N)
{
    __shared__ float wlds[64 * 64];
    __shared__ float bh[64];

    const int tid  = threadIdx.x;
    const int lane = tid & 63;
    const int wave = tid >> 6;

    for (int idx = tid; idx < 64 * 64; idx += 256) wlds[idx] = weight[idx];
    __syncthreads();

    for (int r = wave; r < 64; r += 4) {
        float v  = wlds[r * 64 + lane];
        float ss = waveReduceSum(v * v);
        float n  = fmaxf(sqrtf(ss), EPS);
        wlds[r * 64 + lane] = v * (tanhf(n) / n);
    }
    if (wave == 0) {
        float b  = bias[lane];
        float ss = waveReduceSum(b * b);
        float n  = fmaxf(sqrtf(ss), EPS);
        bh[lane] = b * (tanhf(n) / n);
    }
    __syncthreads();

    const float bd = bh[lane];
    const float y2 = waveReduceSum(bd * bd);

    const int gw = blockIdx.x * 4 + wave;
    const int nw = gridDim.x * 4;
    for (int i = gw; i < N; i += nw) {
        const float* xrow = x + (size_t)i * 64;
        float xv = xrow[lane];
        float ss = waveReduceSum(xv * xv);
        float xn = fmaxf(sqrtf(ss), EPS);
        float xc = fminf(xn, 1.0f - 1e-7f);
        float at = 0.5f * log1pf(2.0f * xc / (1.0f - xc));
        float acc = 0.0f;
        #pragma unroll
        for (int k = 0; k < 64; ++k)
            acc = fmaf(xrow[k], wlds[k * 64 + lane], acc);
        float mss = waveReduceSum(acc * acc);
        float mxn = fmaxf(sqrtf(mss), EPS);
        float hv  = acc * (tanhf(mxn / xn * at) / mxn);
        float x2 = waveReduceSum(hv * hv);
        float xy = waveReduceSum(hv * bd);
        float num = (1.0f + 2.0f * xy + y2) * hv + (1.0f - x2) * bd;
        float den = 1.0f + 2.0f * xy + x2 * y2;
        h[(size_t)i * 64 + lane] = num / fmaxf(den, EPS);
    }
}

// ---------------------------------------------------------------------------
// Phase 2a: degree histogram (int atomics only)
// ---------------------------------------------------------------------------
__global__ __launch_bounds__(256) void hist_kernel(
    const int* __restrict__ dst, int* __restrict__ cnt, int E)
{
    const int stride = gridDim.x * blockDim.x;
    for (int e = blockIdx.x * blockDim.x + threadIdx.x; e < E; e += stride)
        atomicAdd(&cnt[dst[e]], 1);
}

// ---------------------------------------------------------------------------
// Phase 2b: exclusive scan of cnt -> rowptr (+cursor copy)
// ---------------------------------------------------------------------------
__global__ __launch_bounds__(256) void scan_partial(
    const int* __restrict__ cnt, int* __restrict__ pre,
    int* __restrict__ part, int n)
{
    __shared__ int s[256];
    const int tid  = threadIdx.x;
    const int base = blockIdx.x * SCAN_CHUNK + tid * 4;
    int v0 = (base + 0 < n) ? cnt[base + 0] : 0;
    int v1 = (base + 1 < n) ? cnt[base + 1] : 0;
    int v2 = (base + 2 < n) ? cnt[base + 2] : 0;
    int v3 = (base + 3 < n) ? cnt[base + 3] : 0;
    int tsum = v0 + v1 + v2 + v3;
    s[tid] = tsum;
    __syncthreads();
    for (int off = 1; off < 256; off <<= 1) {
        int t = (tid >= off) ? s[tid - off] : 0;
        __syncthreads();
        s[tid] += t;
        __syncthreads();
    }
    int excl = s[tid] - tsum;
    if (base + 0 < n) pre[base + 0] = excl;
    if (base + 1 < n) pre[base + 1] = excl + v0;
    if (base + 2 < n) pre[base + 2] = excl + v0 + v1;
    if (base + 3 < n) pre[base + 3] = excl + v0 + v1 + v2;
    if (tid == 255) part[blockIdx.x] = s[255];
}

__global__ __launch_bounds__(256) void scan_parts(int* __restrict__ part, int nPart)
{
    __shared__ int s[256];
    const int tid = threadIdx.x;
    int v = (tid < nPart) ? part[tid] : 0;
    s[tid] = v;
    __syncthreads();
    for (int off = 1; off < 256; off <<= 1) {
        int t = (tid >= off) ? s[tid - off] : 0;
        __syncthreads();
        s[tid] += t;
        __syncthreads();
    }
    if (tid < nPart) part[tid] = s[tid] - v;  // exclusive
}

__global__ __launch_bounds__(256) void scan_add(
    int* __restrict__ pre, int* __restrict__ cursor,
    const int* __restrict__ part, int n)
{
    const int stride = gridDim.x * blockDim.x;
    for (int i = blockIdx.x * blockDim.x + threadIdx.x; i < n; i += stride) {
        int v = pre[i] + part[i / SCAN_CHUNK];
        pre[i] = v;        // rowptr
        cursor[i] = v;     // bucket cursor
    }
}

// ---------------------------------------------------------------------------
// Phase 2c: XCD-partitioned bucket scatter.
// Group g = blockIdx.x & 7 handles dst range [g*N/8,(g+1)*N/8): under
// round-robin dispatch all writers of one 800 KB bucket region sit on one
// XCD -> region is L2-resident -> lines fill all 16 slots before eviction
// (writeback ~6.4 MB instead of measured 107 MB at round 7).
// Cost: each group re-reads dst[] (8x6.4 MB, L3-absorbed).
// ---------------------------------------------------------------------------
__global__ __launch_bounds__(256) void bucket_kernel(
    const int* __restrict__ src, const int* __restrict__ dst,
    int* __restrict__ cursor, int* __restrict__ bucket, int E, int N)
{
    const int group = blockIdx.x & 7;
    const int gblk  = blockIdx.x >> 3;
    const int nblk  = gridDim.x >> 3;
    const int lo = (int)(((long long)N * group) >> 3);
    const int hi = (int)(((long long)N * (group + 1)) >> 3);
    const int stride = nblk * 256;
    for (int e = gblk * 256 + threadIdx.x; e < E; e += stride) {
        const int d = dst[e];
        if (d >= lo && d < hi) {
            int pos = atomicAdd(&cursor[d], 1);
            bucket[pos] = src[e];
        }
    }
}

// ---------------------------------------------------------------------------
// Phase 3: per-node gather-reduce + mean + projection (unchanged)
// ---------------------------------------------------------------------------
__global__ __launch_bounds__(256) void gather_reduce_kernel(
    const int* __restrict__ rowptr, const int* __restrict__ cnt,
    const int* __restrict__ bucket, const float* __restrict__ h,
    float* __restrict__ out, int N)
{
    const int lane = threadIdx.x & 63;
    const int wave = threadIdx.x >> 6;
    const int i = blockIdx.x * 4 + wave;
    if (i >= N) return;

    const int start = rowptr[i];
    const int deg   = cnt[i];
    const int end   = start + deg;

    float acc = 0.0f;
    for (int c = start; c < end; c += 64) {
        const int m  = min(64, end - c);
        const int my = (lane < m) ? bucket[c + lane] : 0;
        for (int j = 0; j < m; ++j) {
            const int s = __shfl(my, j, 64);
            acc += h[(size_t)s * 64 + lane];
        }
    }

    float v = acc / fmaxf((float)deg, 1.0f);
    float ss = waveReduceSum(v * v);
    float n  = fmaxf(sqrtf(ss), EPS);
    if (n > MAX_NORM) v = v / n * MAX_NORM;
    out[(size_t)i * 64 + lane] = v;
}

extern "C" void kernel_launch(void* const* d_in, const int* in_sizes, int n_in,
                              void* d_out, int out_size, void* d_ws, size_t ws_size,
                              hipStream_t stream)
{
    const float* x      = (const float*)d_in[0];
    const float* weight = (const float*)d_in[1];
    const float* bias   = (const float*)d_in[2];
    const int*   ei     = (const int*)d_in[3];
    const int N = in_sizes[0] / 64;
    const int E = in_sizes[3] / 2;
    const int* src = ei;
    const int* dst = ei + E;

    float* out = (float*)d_out;

    // workspace layout (~33 MB)
    float* h      = (float*)d_ws;               // N*64 floats
    int*   cnt    = (int*)(h + (size_t)N * 64); // N
    int*   rowptr = cnt + N;                    // N
    int*   cursor = rowptr + N;                 // N
    int*   part   = cursor + N;                 // 256
    int*   bucket = part + 256;                 // E

    const int nPart = (N + SCAN_CHUNK - 1) / SCAN_CHUNK;   // 98 for N=100K

    hipMemsetAsync(cnt, 0, (size_t)N * sizeof(int), stream);

    transform_kernel<<<2048, 256, 0, stream>>>(x, weight, bias, h, N);
    hist_kernel<<<2048, 256, 0, stream>>>(dst, cnt, E);
    scan_partial<<<nPart, 256, 0, stream>>>(cnt, rowptr, part, N);
    scan_parts<<<1, 256, 0, stream>>>(part, nPart);
    scan_add<<<256, 256, 0, stream>>>(rowptr, cursor, part, N);
    bucket_kernel<<<2048, 256, 0, stream>>>(src, dst, cursor, bucket, E, N);
    gather_reduce_kernel<<<(N + 3) / 4, 256, 0, stream>>>(rowptr, cnt, bucket, h, out, N);
}